// Round 7
// baseline (218.542 us; speedup 1.0000x reference)
//
#include <hip/hip_runtime.h>
#include <stdint.h>

// Problem constants
#define BB 16
#define CC 512
#define CQK 64
#define NN 1024   // H*W = 32*32

typedef __attribute__((ext_vector_type(8))) short bf16x8;
typedef __attribute__((ext_vector_type(4))) short short4v;
typedef __attribute__((ext_vector_type(4))) float f32x4;

static __device__ __forceinline__ unsigned short f2bf(float f) {
  uint32_t u = __float_as_uint(f);
  u += 0x7FFFu + ((u >> 16) & 1u);
  return (unsigned short)(u >> 16);
}

// Async global->LDS, 16B per lane. LDS dest = wave-uniform base + lane*16.
static __device__ __forceinline__ void gll16(const unsigned short* g, unsigned short* l) {
  const __attribute__((address_space(1))) unsigned int* gp =
      reinterpret_cast<const __attribute__((address_space(1))) unsigned int*>(
          reinterpret_cast<uintptr_t>(g));
  __attribute__((address_space(3))) unsigned int* lp =
      reinterpret_cast<__attribute__((address_space(3))) unsigned int*>(
          (unsigned int)reinterpret_cast<uintptr_t>(l));
  __builtin_amdgcn_global_load_lds(gp, lp, 16, 0, 0);
}

// ---------------------------------------------------------------------------
// Kernel 1: transpose x[b][c][n] (fp32) -> xT[b][n][c] (bf16)
//   + first 320 blocks also pack Wq|Wk|Wv -> bf16 Wall[640][512]
// grid (N/32, C/32, B), block 256   (R6-proven body, unchanged)
// ---------------------------------------------------------------------------
__global__ __launch_bounds__(256) void k_prep(
    const float* __restrict__ x, unsigned short* __restrict__ xT,
    const float* __restrict__ Wq, const float* __restrict__ Wk,
    const float* __restrict__ Wv, unsigned short* __restrict__ Wall) {
  __shared__ float tile[32][33];
  int b = blockIdx.z;
  int c0 = blockIdx.y * 32;
  int n0 = blockIdx.x * 32;
  int t = threadIdx.x;

  int flat = ((int)blockIdx.z * gridDim.y + blockIdx.y) * gridDim.x + blockIdx.x;
  if (flat < 320) {
    int e = (flat * 256 + t) * 4;
    int o = e >> 9;
    int c = e & 511;
    const float* src;
    if (o < 64)        src = Wq + (size_t)o * 512;
    else if (o < 128)  src = Wk + (size_t)(o - 64) * 512;
    else               src = Wv + (size_t)(o - 128) * 512;
    float4 v = *(const float4*)(src + c);
    short4v pk;
    pk[0] = (short)f2bf(v.x); pk[1] = (short)f2bf(v.y);
    pk[2] = (short)f2bf(v.z); pk[3] = (short)f2bf(v.w);
    *(short4v*)(Wall + e) = pk;
  }

  int tn = t & 31, tc = t >> 5;  // tc 0..7
  const float* xp = x + ((size_t)b * CC + c0) * NN + n0;
#pragma unroll
  for (int i = 0; i < 4; i++) {
    int c = tc + i * 8;
    tile[c][tn] = xp[(size_t)c * NN + tn];
  }
  __syncthreads();
  unsigned short* xq = xT + ((size_t)b * NN + n0) * CC + c0;
  int n = t >> 3;
  int cq = (t & 7) * 4;
  short4v pk;
#pragma unroll
  for (int k = 0; k < 4; k++) pk[k] = (short)f2bf(tile[cq + k][n]);
  *(short4v*)(&xq[(size_t)n * CC + cq]) = pk;
}

// ---------------------------------------------------------------------------
// Kernel 2: GEMM1  (R1-proven body, unchanged)
// ---------------------------------------------------------------------------
__global__ __launch_bounds__(256) void k_gemm1(
    const unsigned short* __restrict__ Wall, const unsigned short* __restrict__ xT,
    const float* __restrict__ bq, const float* __restrict__ bk,
    const float* __restrict__ bv,
    unsigned short* __restrict__ qkT, unsigned short* __restrict__ vbuf) {
  __shared__ __align__(16) unsigned short ldsA[2][128 * 32];
  __shared__ __align__(16) unsigned short ldsB[2][128 * 32];
  int bid = blockIdx.x;
  int swz = (bid & 7) * 80 + (bid >> 3);
  int nx = swz & 7;
  int rest = swz >> 3;
  int oy = rest % 5;
  int b = rest / 5;
  int o0 = oy * 128;
  int n0 = nx * 128;
  int t = threadIdx.x;
  int w = t >> 6, l = t & 63;
  int wm = w & 1, wn = w >> 1;
  int lr = l & 15, lq = l >> 4;

  f32x4 acc[4][4];
#pragma unroll
  for (int i = 0; i < 4; i++)
#pragma unroll
    for (int j = 0; j < 4; j++) acc[i][j] = (f32x4){0.f, 0.f, 0.f, 0.f};

  const unsigned short* Ab = Wall + (size_t)o0 * CC;
  const unsigned short* Bb = xT + ((size_t)b * NN + n0) * CC;
  int srow = t >> 2;
  int skq = (t & 3) * 8;
  int ldsw = (t >> 6) * 512;

#pragma unroll
  for (int p = 0; p < 2; p++) {
    int r = p * 64 + srow;
    gll16(&Ab[(size_t)r * CC + skq], &ldsA[0][p * 2048 + ldsw]);
    gll16(&Bb[(size_t)r * CC + skq], &ldsB[0][p * 2048 + ldsw]);
  }
  __syncthreads();

  for (int s = 0; s < 16; ++s) {
    int cur = s & 1;
    if (s + 1 < 16) {
      int kt = (s + 1) * 32;
#pragma unroll
      for (int p = 0; p < 2; p++) {
        int r = p * 64 + srow;
        gll16(&Ab[(size_t)r * CC + kt + skq], &ldsA[cur ^ 1][p * 2048 + ldsw]);
        gll16(&Bb[(size_t)r * CC + kt + skq], &ldsB[cur ^ 1][p * 2048 + ldsw]);
      }
    }
    bf16x8 af[4], bfr[4];
#pragma unroll
    for (int i = 0; i < 4; i++)
      af[i] = *(const bf16x8*)(&ldsA[cur][(wm * 64 + i * 16 + lr) * 32 + lq * 8]);
#pragma unroll
    for (int j = 0; j < 4; j++)
      bfr[j] = *(const bf16x8*)(&ldsB[cur][(wn * 64 + j * 16 + lr) * 32 + lq * 8]);
#pragma unroll
    for (int i = 0; i < 4; i++)
#pragma unroll
      for (int j = 0; j < 4; j++)
        acc[i][j] = __builtin_amdgcn_mfma_f32_16x16x32_bf16(af[i], bfr[j], acc[i][j], 0, 0, 0);
    __syncthreads();
  }

  if (o0 == 0) {
#pragma unroll
    for (int i = 0; i < 4; i++) {
      int ob = wm * 64 + i * 16 + lq * 4;
#pragma unroll
      for (int j = 0; j < 4; j++) {
        int n = n0 + wn * 64 + j * 16 + lr;
        short4v pk;
#pragma unroll
        for (int r = 0; r < 4; r++) {
          int o = ob + r;
          float bias = (o < 64) ? bq[o] : bk[o - 64];
          pk[r] = (short)f2bf(acc[i][j][r] + bias);
        }
        *(short4v*)(&qkT[((size_t)b * NN + n) * 128 + ob]) = pk;
      }
    }
  } else {
#pragma unroll
    for (int i = 0; i < 4; i++) {
#pragma unroll
      for (int r = 0; r < 4; r++) {
        int o = o0 + wm * 64 + i * 16 + lq * 4 + r;
        int c = o - 128;
        float bias = bv[c];
#pragma unroll
        for (int j = 0; j < 4; j++) {
          int n = n0 + wn * 64 + j * 16 + lr;
          vbuf[((size_t)b * CC + c) * NN + n] = f2bf(acc[i][j][r] + bias);
        }
      }
    }
  }
}

// ---------------------------------------------------------------------------
// Kernel 3: one-pass flash — QT 64->32 query split (this round's single
//   change). Grid 1024 = 4 blocks/CU = 4 waves/SIMD with ZERO extra work:
//   QK^T duplication stays x2 (chalf), PV volume unchanged; only per-block
//   Q-frag loads duplicate (~2KB). R2's occupancy attempt failed because it
//   duplicated QK^T x4; this splits N instead. Waves on one SIMD now come
//   from 4 INDEPENDENT blocks (uncorrelated barrier phases) -> the ~80%
//   issue-idle measured in R1/R6 gets filled.
//   Keeps R6's chunk-deep V/K register pipeline.
// ---------------------------------------------------------------------------
#define QT 32
#define MC 64
#define PSTR 72  // ushort units; 144B row stride

__global__ __launch_bounds__(256, 4) void k_flash(
    const unsigned short* __restrict__ qkT, const unsigned short* __restrict__ vbuf,
    const float* __restrict__ x, const float* __restrict__ gamma,
    float* __restrict__ out) {
  __shared__ __align__(16) unsigned short P[QT * PSTR];  // 4608 B
  __shared__ float red[4 * QT];                          // 512 B
  __shared__ float fin[QT];                              // 128 B

  // XCD-aware swizzle: hw block h -> logical (h%8)*128 + h/8 (1024 = 8*128).
  int bid = blockIdx.x;
  int swz = (bid & 7) * 128 + (bid >> 3);
  int ntile = swz & 31;          // 32 n-tiles of 32 rows
  int chalf = (swz >> 5) & 1;
  int b = swz >> 6;
  int n0 = ntile * QT;
  int t = threadIdx.x;
  int w = t >> 6, l = t & 63;
  int lr = l & 15, lq = l >> 4;
  int lq8 = lq * 8;
  const unsigned short* qk = qkT + (size_t)b * NN * 128;
  const unsigned short* Vb = vbuf + ((size_t)b * CC + chalf * 256 + w * 64) * NN;

  // Q fragments (constant over all chunks): 2 nj blocks of 16 rows
  bf16x8 aq[2][2];
#pragma unroll
  for (int nj = 0; nj < 2; nj++)
#pragma unroll
    for (int ks = 0; ks < 2; ks++)
      aq[nj][ks] = *(const bf16x8*)(&qk[(size_t)(n0 + nj * 16 + lr) * 128 + ks * 32 + lq8]);

  f32x4 acc[4][2];  // [ci][nj]
#pragma unroll
  for (int ci = 0; ci < 4; ci++)
#pragma unroll
    for (int nj = 0; nj < 2; nj++) acc[ci][nj] = (f32x4){0.f, 0.f, 0.f, 0.f};
  float sreg[2][4];
#pragma unroll
  for (int nj = 0; nj < 2; nj++)
#pragma unroll
    for (int r = 0; r < 4; r++) sreg[nj][r] = 0.f;

  // Prologue: V ks0 for chunk 0; K for chunk MC; exp(S) for chunk 0.
  bf16x8 vA[4];
#pragma unroll
  for (int ci = 0; ci < 4; ci++)
    vA[ci] = *(const bf16x8*)(&Vb[(size_t)(ci * 16 + lr) * NN + lq8]);
  bf16x8 kf0c, kf1c;
  {
    int mrow = MC + w * 16 + lr;
    kf0c = *(const bf16x8*)(&qk[(size_t)mrow * 128 + 64 + lq8]);
    kf1c = *(const bf16x8*)(&qk[(size_t)mrow * 128 + 96 + lq8]);
  }
  float ev[2][4];
  {
    int mrow = w * 16 + lr;  // m0 = 0
    bf16x8 kf0 = *(const bf16x8*)(&qk[(size_t)mrow * 128 + 64 + lq8]);
    bf16x8 kf1 = *(const bf16x8*)(&qk[(size_t)mrow * 128 + 96 + lq8]);
#pragma unroll
    for (int nj = 0; nj < 2; nj++) {
      f32x4 s = (f32x4){0.f, 0.f, 0.f, 0.f};
      s = __builtin_amdgcn_mfma_f32_16x16x32_bf16(aq[nj][0], kf0, s, 0, 0, 0);
      s = __builtin_amdgcn_mfma_f32_16x16x32_bf16(aq[nj][1], kf1, s, 0, 0, 0);
#pragma unroll
      for (int r = 0; r < 4; r++) {
        float e = __expf(s[r]);
        ev[nj][r] = e;
        sreg[nj][r] += e;
      }
    }
  }

  for (int m0 = 0; m0 < NN; m0 += MC) {
    bool hn = (m0 + MC < NN);
    // Current-chunk V ks1.
    bf16x8 vB[4];
#pragma unroll
    for (int ci = 0; ci < 4; ci++)
      vB[ci] = *(const bf16x8*)(&Vb[(size_t)(ci * 16 + lr) * NN + m0 + 32 + lq8]);
    // NEXT-chunk V ks0 (consumed one full iteration from now).
    bf16x8 vAn[4];
    if (hn) {
#pragma unroll
      for (int ci = 0; ci < 4; ci++)
        vAn[ci] = *(const bf16x8*)(&Vb[(size_t)(ci * 16 + lr) * NN + m0 + MC + lq8]);
    }
    // K for chunk m0+2*MC (consumed next iteration's S-compute).
    bf16x8 kf0n, kf1n;
    if (m0 + 2 * MC < NN) {
      int mrow = m0 + 2 * MC + w * 16 + lr;
      kf0n = *(const bf16x8*)(&qk[(size_t)mrow * 128 + 64 + lq8]);
      kf1n = *(const bf16x8*)(&qk[(size_t)mrow * 128 + 96 + lq8]);
    }

    __syncthreads();  // all PV reads of previous chunk's P complete
#pragma unroll
    for (int nj = 0; nj < 2; nj++)
#pragma unroll
      for (int r = 0; r < 4; r++)
        P[(nj * 16 + lq * 4 + r) * PSTR + w * 16 + lr] = f2bf(ev[nj][r]);

    // Scores+exp for NEXT chunk (K loaded one iteration ago).
    if (hn) {
#pragma unroll
      for (int nj = 0; nj < 2; nj++) {
        f32x4 s = (f32x4){0.f, 0.f, 0.f, 0.f};
        s = __builtin_amdgcn_mfma_f32_16x16x32_bf16(aq[nj][0], kf0c, s, 0, 0, 0);
        s = __builtin_amdgcn_mfma_f32_16x16x32_bf16(aq[nj][1], kf1c, s, 0, 0, 0);
#pragma unroll
        for (int r = 0; r < 4; r++) {
          float e = __expf(s[r]);
          ev[nj][r] = e;
          sreg[nj][r] += e;
        }
      }
    }
    __syncthreads();  // P ready

    // PV ks=0
#pragma unroll
    for (int nj = 0; nj < 2; nj++) {
      bf16x8 pf = *(const bf16x8*)(&P[(nj * 16 + lr) * PSTR + lq8]);
#pragma unroll
      for (int ci = 0; ci < 4; ci++)
        acc[ci][nj] = __builtin_amdgcn_mfma_f32_16x16x32_bf16(vA[ci], pf, acc[ci][nj], 0, 0, 0);
    }
    // PV ks=1
#pragma unroll
    for (int nj = 0; nj < 2; nj++) {
      bf16x8 pf = *(const bf16x8*)(&P[(nj * 16 + lr) * PSTR + 32 + lq8]);
#pragma unroll
      for (int ci = 0; ci < 4; ci++)
        acc[ci][nj] = __builtin_amdgcn_mfma_f32_16x16x32_bf16(vB[ci], pf, acc[ci][nj], 0, 0, 0);
    }

    if (hn) {
#pragma unroll
      for (int ci = 0; ci < 4; ci++) vA[ci] = vAn[ci];
      kf0c = kf0n;
      kf1c = kf1n;
    }
  }

  // ---- final row sums (across 16 lr lanes, then 4 waves) ----
#pragma unroll
  for (int nj = 0; nj < 2; nj++)
#pragma unroll
    for (int r = 0; r < 4; r++) {
#pragma unroll
      for (int d = 1; d < 16; d <<= 1) sreg[nj][r] += __shfl_xor(sreg[nj][r], d, 64);
    }
  __syncthreads();
  if (lr == 0) {
#pragma unroll
    for (int nj = 0; nj < 2; nj++)
#pragma unroll
      for (int r = 0; r < 4; r++) red[w * QT + nj * 16 + lq * 4 + r] = sreg[nj][r];
  }
  __syncthreads();
  if (t < QT) {
    float ssum = red[t] + red[QT + t] + red[2 * QT + t] + red[3 * QT + t];
    fin[t] = ssum;
  }
  __syncthreads();

  float invL[2];
#pragma unroll
  for (int nj = 0; nj < 2; nj++) invL[nj] = 1.0f / fin[nj * 16 + lr];
  float g = gamma[0];
#pragma unroll
  for (int ci = 0; ci < 4; ci++) {
#pragma unroll
    for (int r = 0; r < 4; r++) {
      int c = chalf * 256 + w * 64 + ci * 16 + lq * 4 + r;
#pragma unroll
      for (int nj = 0; nj < 2; nj++) {
        size_t idx = ((size_t)b * CC + c) * NN + n0 + nj * 16 + lr;
        out[idx] = g * acc[ci][nj][r] * invL[nj] + x[idx];
      }
    }
  }
}

// ---------------------------------------------------------------------------
extern "C" void kernel_launch(void* const* d_in, const int* in_sizes, int n_in,
                              void* d_out, int out_size, void* d_ws, size_t ws_size,
                              hipStream_t stream) {
  (void)in_sizes; (void)n_in; (void)out_size; (void)ws_size;
  const float* x     = (const float*)d_in[0];
  const float* Wq    = (const float*)d_in[1];
  const float* bq    = (const float*)d_in[2];
  const float* Wk    = (const float*)d_in[3];
  const float* bk    = (const float*)d_in[4];
  const float* Wv    = (const float*)d_in[5];
  const float* bv    = (const float*)d_in[6];
  const float* gamma = (const float*)d_in[7];
  float* out = (float*)d_out;

  char* ws = (char*)d_ws;
  unsigned short* Wall = (unsigned short*)(ws);                       // 655,360 B
  unsigned short* xT   = (unsigned short*)(ws + 655360);              // 16,777,216 B
  unsigned short* qkT  = (unsigned short*)(ws + 655360 + 16777216);   // 4,194,304 B
  unsigned short* vbuf = (unsigned short*)(ws + 655360 + 16777216 + 4194304);  // 16,777,216 B
  // total ~38.4 MB

  k_prep<<<dim3(NN / 32, CC / 32, BB), dim3(256), 0, stream>>>(x, xT, Wq, Wk, Wv, Wall);
  k_gemm1<<<dim3(640), dim3(256), 0, stream>>>(Wall, xT, bq, bk, bv, qkT, vbuf);
  k_flash<<<dim3(1024), dim3(256), 0, stream>>>(qkT, vbuf, x, gamma, out);
}

// Round 8
// 163.417 us; speedup vs baseline: 1.3373x; 1.3373x over previous
//
#include <hip/hip_runtime.h>
#include <stdint.h>

// Problem constants
#define BB 16
#define CC 512
#define CQK 64
#define NN 1024   // H*W = 32*32

typedef __attribute__((ext_vector_type(8))) short bf16x8;
typedef __attribute__((ext_vector_type(4))) short short4v;
typedef __attribute__((ext_vector_type(4))) float f32x4;

static __device__ __forceinline__ unsigned short f2bf(float f) {
  uint32_t u = __float_as_uint(f);
  u += 0x7FFFu + ((u >> 16) & 1u);
  return (unsigned short)(u >> 16);
}

// Async global->LDS, 16B per lane. LDS dest = wave-uniform base + lane*16.
static __device__ __forceinline__ void gll16(const unsigned short* g, unsigned short* l) {
  const __attribute__((address_space(1))) unsigned int* gp =
      reinterpret_cast<const __attribute__((address_space(1))) unsigned int*>(
          reinterpret_cast<uintptr_t>(g));
  __attribute__((address_space(3))) unsigned int* lp =
      reinterpret_cast<__attribute__((address_space(3))) unsigned int*>(
          (unsigned int)reinterpret_cast<uintptr_t>(l));
  __builtin_amdgcn_global_load_lds(gp, lp, 16, 0, 0);
}

// ---------------------------------------------------------------------------
// Kernel 1 (REBUILT for BW): transpose x[b][c][n] fp32 -> xT[b][n][c] bf16.
//   64x64 tiles, 2048 blocks (was 32x32 / 8192): per thread 4x float4 global
//   loads (16B), LDS fp32 tile padded to 65 (transpose reads = 2-way bank
//   alias, free), two 16B bf16 stores. 4x fewer load instrs per byte.
//   First 320 blocks also pack Wq|Wk|Wv -> Wall.
// grid (N/64=16, C/64=8, B=16), block 256
// ---------------------------------------------------------------------------
__global__ __launch_bounds__(256) void k_prep(
    const float* __restrict__ x, unsigned short* __restrict__ xT,
    const float* __restrict__ Wq, const float* __restrict__ Wk,
    const float* __restrict__ Wv, unsigned short* __restrict__ Wall) {
  __shared__ float tile[64][65];  // 16.6 KB
  int b = blockIdx.z;
  int c0 = blockIdx.y * 64;
  int n0 = blockIdx.x * 64;
  int t = threadIdx.x;

  // fused weight pack (640*512 / 4 / 256 = 320 blocks)
  int flat = ((int)blockIdx.z * gridDim.y + blockIdx.y) * gridDim.x + blockIdx.x;
  if (flat < 320) {
    int e = (flat * 256 + t) * 4;
    int o = e >> 9;
    int c = e & 511;
    const float* src;
    if (o < 64)        src = Wq + (size_t)o * 512;
    else if (o < 128)  src = Wk + (size_t)(o - 64) * 512;
    else               src = Wv + (size_t)(o - 128) * 512;
    float4 v = *(const float4*)(src + c);
    short4v pk;
    pk[0] = (short)f2bf(v.x); pk[1] = (short)f2bf(v.y);
    pk[2] = (short)f2bf(v.z); pk[3] = (short)f2bf(v.w);
    *(short4v*)(Wall + e) = pk;
  }

  int r = t >> 2;        // 0..63 : c-row within tile
  int cg = t & 3;        // 0..3  : 16-float column group
  const float* xp = x + ((size_t)(b * CC + c0 + r)) * NN + n0;
#pragma unroll
  for (int k = 0; k < 4; k++) {
    float4 v = *(const float4*)(xp + k * 16 + cg * 4);
    int cb = k * 16 + cg * 4;
    tile[r][cb + 0] = v.x;
    tile[r][cb + 1] = v.y;
    tile[r][cb + 2] = v.z;
    tile[r][cb + 3] = v.w;
  }
  __syncthreads();

  int n = t >> 2;        // 0..63 : n-row of output
  unsigned short* xq = xT + ((size_t)(b * NN + n0 + n)) * CC + c0 + cg * 16;
  short4v p[4];
#pragma unroll
  for (int q = 0; q < 4; q++) {
#pragma unroll
    for (int j = 0; j < 4; j++) p[q][j] = (short)f2bf(tile[cg * 16 + q * 4 + j][n]);
  }
  // two 16B stores (32B-aligned: c-index multiple of 16)
  *(short4v*)(xq + 0) = p[0];
  *(short4v*)(xq + 4) = p[1];
  *(short4v*)(xq + 8) = p[2];
  *(short4v*)(xq + 12) = p[3];
}

// ---------------------------------------------------------------------------
// Kernel 2: GEMM1  (R1-proven body, unchanged)
// ---------------------------------------------------------------------------
__global__ __launch_bounds__(256) void k_gemm1(
    const unsigned short* __restrict__ Wall, const unsigned short* __restrict__ xT,
    const float* __restrict__ bq, const float* __restrict__ bk,
    const float* __restrict__ bv,
    unsigned short* __restrict__ qkT, unsigned short* __restrict__ vbuf) {
  __shared__ __align__(16) unsigned short ldsA[2][128 * 32];
  __shared__ __align__(16) unsigned short ldsB[2][128 * 32];
  int bid = blockIdx.x;
  int swz = (bid & 7) * 80 + (bid >> 3);
  int nx = swz & 7;
  int rest = swz >> 3;
  int oy = rest % 5;
  int b = rest / 5;
  int o0 = oy * 128;
  int n0 = nx * 128;
  int t = threadIdx.x;
  int w = t >> 6, l = t & 63;
  int wm = w & 1, wn = w >> 1;
  int lr = l & 15, lq = l >> 4;

  f32x4 acc[4][4];
#pragma unroll
  for (int i = 0; i < 4; i++)
#pragma unroll
    for (int j = 0; j < 4; j++) acc[i][j] = (f32x4){0.f, 0.f, 0.f, 0.f};

  const unsigned short* Ab = Wall + (size_t)o0 * CC;
  const unsigned short* Bb = xT + ((size_t)b * NN + n0) * CC;
  int srow = t >> 2;
  int skq = (t & 3) * 8;
  int ldsw = (t >> 6) * 512;

#pragma unroll
  for (int p = 0; p < 2; p++) {
    int r = p * 64 + srow;
    gll16(&Ab[(size_t)r * CC + skq], &ldsA[0][p * 2048 + ldsw]);
    gll16(&Bb[(size_t)r * CC + skq], &ldsB[0][p * 2048 + ldsw]);
  }
  __syncthreads();

  for (int s = 0; s < 16; ++s) {
    int cur = s & 1;
    if (s + 1 < 16) {
      int kt = (s + 1) * 32;
#pragma unroll
      for (int p = 0; p < 2; p++) {
        int r = p * 64 + srow;
        gll16(&Ab[(size_t)r * CC + kt + skq], &ldsA[cur ^ 1][p * 2048 + ldsw]);
        gll16(&Bb[(size_t)r * CC + kt + skq], &ldsB[cur ^ 1][p * 2048 + ldsw]);
      }
    }
    bf16x8 af[4], bfr[4];
#pragma unroll
    for (int i = 0; i < 4; i++)
      af[i] = *(const bf16x8*)(&ldsA[cur][(wm * 64 + i * 16 + lr) * 32 + lq * 8]);
#pragma unroll
    for (int j = 0; j < 4; j++)
      bfr[j] = *(const bf16x8*)(&ldsB[cur][(wn * 64 + j * 16 + lr) * 32 + lq * 8]);
#pragma unroll
    for (int i = 0; i < 4; i++)
#pragma unroll
      for (int j = 0; j < 4; j++)
        acc[i][j] = __builtin_amdgcn_mfma_f32_16x16x32_bf16(af[i], bfr[j], acc[i][j], 0, 0, 0);
    __syncthreads();
  }

  if (o0 == 0) {
#pragma unroll
    for (int i = 0; i < 4; i++) {
      int ob = wm * 64 + i * 16 + lq * 4;
#pragma unroll
      for (int j = 0; j < 4; j++) {
        int n = n0 + wn * 64 + j * 16 + lr;
        short4v pk;
#pragma unroll
        for (int r = 0; r < 4; r++) {
          int o = ob + r;
          float bias = (o < 64) ? bq[o] : bk[o - 64];
          pk[r] = (short)f2bf(acc[i][j][r] + bias);
        }
        *(short4v*)(&qkT[((size_t)b * NN + n) * 128 + ob]) = pk;
      }
    }
  } else {
#pragma unroll
    for (int i = 0; i < 4; i++) {
#pragma unroll
      for (int r = 0; r < 4; r++) {
        int o = o0 + wm * 64 + i * 16 + lq * 4 + r;
        int c = o - 128;
        float bias = bv[c];
#pragma unroll
        for (int j = 0; j < 4; j++) {
          int n = n0 + wn * 64 + j * 16 + lr;
          vbuf[((size_t)b * CC + c) * NN + n] = f2bf(acc[i][j][r] + bias);
        }
      }
    }
  }
}

// ---------------------------------------------------------------------------
// Kernel 3: one-pass flash — EXACT R1-proven body (52.8 us): 512 blocks,
//   2-way c-split, acc[4][4], V ks0 + next-K prefetch at chunk top, V ks1
//   after barrier2. All occupancy/pipeline variants (R2,R6,R7) were neutral
//   or regressions; the limit is the per-chunk serial chain.
// ---------------------------------------------------------------------------
#define QT 64
#define MC 64
#define PSTR 72  // ushort units; 144B row stride (16B-aligned, 2-way banks = free)

__global__ __launch_bounds__(256, 2) void k_flash(
    const unsigned short* __restrict__ qkT, const unsigned short* __restrict__ vbuf,
    const float* __restrict__ x, const float* __restrict__ gamma,
    float* __restrict__ out) {
  __shared__ __align__(16) unsigned short P[QT * PSTR];  // 9216 B
  __shared__ float red[4 * QT];                          // 1024 B
  __shared__ float fin[QT];                              // 256 B

  // XCD-aware swizzle: hw block h -> logical id (h%8)*64 + h/8 (512 = 8*64).
  int bid = blockIdx.x;
  int swz = (bid & 7) * 64 + (bid >> 3);
  int ntile = swz & 15;
  int chalf = (swz >> 4) & 1;
  int b = swz >> 5;
  int n0 = ntile * QT;
  int t = threadIdx.x;
  int w = t >> 6, l = t & 63;
  int lr = l & 15, lq = l >> 4;
  const unsigned short* qk = qkT + (size_t)b * NN * 128;
  const unsigned short* Vb = vbuf + ((size_t)b * CC + chalf * 256 + w * 64) * NN;

  // Q fragments (constant over all chunks)
  bf16x8 aq[4][2];
#pragma unroll
  for (int nj = 0; nj < 4; nj++)
#pragma unroll
    for (int ks = 0; ks < 2; ks++)
      aq[nj][ks] = *(const bf16x8*)(&qk[(size_t)(n0 + nj * 16 + lr) * 128 + ks * 32 + lq * 8]);

  f32x4 acc[4][4];  // [ci][nj]
#pragma unroll
  for (int ci = 0; ci < 4; ci++)
#pragma unroll
    for (int nj = 0; nj < 4; nj++) acc[ci][nj] = (f32x4){0.f, 0.f, 0.f, 0.f};
  float sreg[4][4];
#pragma unroll
  for (int nj = 0; nj < 4; nj++)
#pragma unroll
    for (int r = 0; r < 4; r++) sreg[nj][r] = 0.f;

  // Prologue: scores+exp for chunk 0
  float ev[4][4];
  {
    int mrow = w * 16 + lr;  // m0 = 0
    bf16x8 kf0 = *(const bf16x8*)(&qk[(size_t)mrow * 128 + 64 + lq * 8]);
    bf16x8 kf1 = *(const bf16x8*)(&qk[(size_t)mrow * 128 + 96 + lq * 8]);
#pragma unroll
    for (int nj = 0; nj < 4; nj++) {
      f32x4 s = (f32x4){0.f, 0.f, 0.f, 0.f};
      s = __builtin_amdgcn_mfma_f32_16x16x32_bf16(aq[nj][0], kf0, s, 0, 0, 0);
      s = __builtin_amdgcn_mfma_f32_16x16x32_bf16(aq[nj][1], kf1, s, 0, 0, 0);
#pragma unroll
      for (int r = 0; r < 4; r++) {
        float e = __expf(s[r]);
        ev[nj][r] = e;
        sreg[nj][r] += e;
      }
    }
  }

  for (int m0 = 0; m0 < NN; m0 += MC) {
    // Prefetch V fragments for ks=0 of this chunk.
    bf16x8 af0[4];
#pragma unroll
    for (int ci = 0; ci < 4; ci++)
      af0[ci] = *(const bf16x8*)(&Vb[(size_t)(ci * 16 + lr) * NN + m0 + lq * 8]);

    // Prefetch next-chunk K fragments early (consumed after barrier 1).
    bf16x8 kf0n, kf1n;
    if (m0 + MC < NN) {
      int mrow = m0 + MC + w * 16 + lr;
      kf0n = *(const bf16x8*)(&qk[(size_t)mrow * 128 + 64 + lq * 8]);
      kf1n = *(const bf16x8*)(&qk[(size_t)mrow * 128 + 96 + lq * 8]);
    }

    __syncthreads();  // all PV reads of previous chunk's P complete
#pragma unroll
    for (int nj = 0; nj < 4; nj++)
#pragma unroll
      for (int r = 0; r < 4; r++)
        P[(nj * 16 + lq * 4 + r) * PSTR + w * 16 + lr] = f2bf(ev[nj][r]);

    // Compute scores+exp for NEXT chunk while P settles.
    if (m0 + MC < NN) {
#pragma unroll
      for (int nj = 0; nj < 4; nj++) {
        f32x4 s = (f32x4){0.f, 0.f, 0.f, 0.f};
        s = __builtin_amdgcn_mfma_f32_16x16x32_bf16(aq[nj][0], kf0n, s, 0, 0, 0);
        s = __builtin_amdgcn_mfma_f32_16x16x32_bf16(aq[nj][1], kf1n, s, 0, 0, 0);
#pragma unroll
        for (int r = 0; r < 4; r++) {
          float e = __expf(s[r]);
          ev[nj][r] = e;
          sreg[nj][r] += e;
        }
      }
    }
    __syncthreads();  // P ready

    // Prefetch V for ks=1 (latency hidden by ks=0 MFMAs).
    bf16x8 af1[4];
#pragma unroll
    for (int ci = 0; ci < 4; ci++)
      af1[ci] = *(const bf16x8*)(&Vb[(size_t)(ci * 16 + lr) * NN + m0 + 32 + lq * 8]);

    // PV ks=0
#pragma unroll
    for (int nj = 0; nj < 4; nj++) {
      bf16x8 pf = *(const bf16x8*)(&P[(nj * 16 + lr) * PSTR + lq * 8]);
#pragma unroll
      for (int ci = 0; ci < 4; ci++)
        acc[ci][nj] = __builtin_amdgcn_mfma_f32_16x16x32_bf16(af0[ci], pf, acc[ci][nj], 0, 0, 0);
    }
    // PV ks=1
#pragma unroll
    for (int nj = 0; nj < 4; nj++) {
      bf16x8 pf = *(const bf16x8*)(&P[(nj * 16 + lr) * PSTR + 32 + lq * 8]);
#pragma unroll
      for (int ci = 0; ci < 4; ci++)
        acc[ci][nj] = __builtin_amdgcn_mfma_f32_16x16x32_bf16(af1[ci], pf, acc[ci][nj], 0, 0, 0);
    }
  }

  // ---- final row sums (across 16 lr lanes, then 4 waves) ----
#pragma unroll
  for (int nj = 0; nj < 4; nj++)
#pragma unroll
    for (int r = 0; r < 4; r++) {
#pragma unroll
      for (int d = 1; d < 16; d <<= 1) sreg[nj][r] += __shfl_xor(sreg[nj][r], d, 64);
    }
  __syncthreads();
  if (lr == 0) {
#pragma unroll
    for (int nj = 0; nj < 4; nj++)
#pragma unroll
      for (int r = 0; r < 4; r++) red[w * QT + nj * 16 + lq * 4 + r] = sreg[nj][r];
  }
  __syncthreads();
  if (t < QT) {
    float ssum = red[t] + red[QT + t] + red[2 * QT + t] + red[3 * QT + t];
    fin[t] = ssum;
  }
  __syncthreads();

  float invL[4];
#pragma unroll
  for (int nj = 0; nj < 4; nj++) invL[nj] = 1.0f / fin[nj * 16 + lr];
  float g = gamma[0];
#pragma unroll
  for (int ci = 0; ci < 4; ci++) {
#pragma unroll
    for (int r = 0; r < 4; r++) {
      int c = chalf * 256 + w * 64 + ci * 16 + lq * 4 + r;
#pragma unroll
      for (int nj = 0; nj < 4; nj++) {
        size_t idx = ((size_t)b * CC + c) * NN + n0 + nj * 16 + lr;
        out[idx] = g * acc[ci][nj][r] * invL[nj] + x[idx];
      }
    }
  }
}

// ---------------------------------------------------------------------------
extern "C" void kernel_launch(void* const* d_in, const int* in_sizes, int n_in,
                              void* d_out, int out_size, void* d_ws, size_t ws_size,
                              hipStream_t stream) {
  (void)in_sizes; (void)n_in; (void)out_size; (void)ws_size;
  const float* x     = (const float*)d_in[0];
  const float* Wq    = (const float*)d_in[1];
  const float* bq    = (const float*)d_in[2];
  const float* Wk    = (const float*)d_in[3];
  const float* bk    = (const float*)d_in[4];
  const float* Wv    = (const float*)d_in[5];
  const float* bv    = (const float*)d_in[6];
  const float* gamma = (const float*)d_in[7];
  float* out = (float*)d_out;

  char* ws = (char*)d_ws;
  unsigned short* Wall = (unsigned short*)(ws);                       // 655,360 B
  unsigned short* xT   = (unsigned short*)(ws + 655360);              // 16,777,216 B
  unsigned short* qkT  = (unsigned short*)(ws + 655360 + 16777216);   // 4,194,304 B
  unsigned short* vbuf = (unsigned short*)(ws + 655360 + 16777216 + 4194304);  // 16,777,216 B
  // total ~38.4 MB

  k_prep<<<dim3(NN / 64, CC / 64, BB), dim3(256), 0, stream>>>(x, xT, Wq, Wk, Wv, Wall);
  k_gemm1<<<dim3(640), dim3(256), 0, stream>>>(Wall, xT, bq, bk, bv, qkT, vbuf);
  k_flash<<<dim3(512), dim3(256), 0, stream>>>(qkT, vbuf, x, gamma, out);
}